// Round 3
// baseline (70.399 us; speedup 1.0000x reference)
//
#include <hip/hip_runtime.h>

// Chamfer distance, fp32 brute force, VALU-bound.
// rows 0..32767    : predict points (b = r>>13), cols = target[b]
// rows 32768..65535: target points,              cols = predict[b]
// Per row: min over 8192 cols of (||t||^2 - 2 p.t), then + ||p||^2.
// out = (sum over all 65536 rows) / 32768.
//
// Inner: q = -2p per row; s = fma(qx,tx,fma(qy,ty,fma(qz,tz,tw))) = 3 fma;
// column pairs folded with fminf(fminf(mn,s0),s1) -> v_min3_f32.
// 3.5 VALU/pair -> ~24 us floor at full issue.
// __launch_bounds__(256,2): VGPR cap 256 so the 80-reg row state stays
// live (R1's (256) default capped at 44 VGPR -> compiler fissioned the
// j-loop, 4x LDS reads, latency exposed).

#define NPTS   8192
#define HALF   32768            // 4 * NPTS
#define NROWS  65536
#define P      16               // rows per thread
#define RPB    4096             // rows per block = 256 * P
#define NRB    16               // NROWS / RPB

__global__ __launch_bounds__(256) void pack_kernel(
    const float* __restrict__ predict, const float* __restrict__ target,
    float4* __restrict__ packed)
{
    int r = blockIdx.x * 256 + threadIdx.x;
    const float* src = (r < HALF) ? (predict + (size_t)r * 3)
                                  : (target + (size_t)(r - HALF) * 3);
    float x = src[0], y = src[1], z = src[2];
    float nrm = fmaf(x, x, fmaf(y, y, z * z));
    packed[r] = make_float4(x, y, z, nrm);
}

template<int NCH>
__global__ __launch_bounds__(256, 2) void minpart_kernel(
    const float4* __restrict__ packed, float* __restrict__ partial)
{
    constexpr int CW = NPTS / NCH;            // cols per chunk
    __shared__ float4 sm[CW];
    const int rb   = blockIdx.x / NCH;
    const int cb   = blockIdx.x % NCH;
    const int row0 = rb * RPB;
    const bool sideA = (row0 < HALF);
    const int local = sideA ? row0 : row0 - HALF;
    const int b = local >> 13;                // / NPTS
    const int colBase = (sideA ? HALF : 0) + (b << 13) + cb * CW;

    for (int i = threadIdx.x; i < CW; i += 256)
        sm[i] = packed[colBase + i];
    __syncthreads();

    float qx[P], qy[P], qz[P], mn[P];
    #pragma unroll
    for (int j = 0; j < P; ++j) {
        float4 p = packed[row0 + threadIdx.x + j * 256];
        qx[j] = -2.0f * p.x; qy[j] = -2.0f * p.y; qz[j] = -2.0f * p.z;
        mn[j] = 3.4e38f;
    }

    // register-rotated prefetch: load next column pair, compute current
    float4 c0 = sm[0], c1 = sm[1];
    #pragma unroll 1
    for (int i = 2; i < CW; i += 2) {
        float4 n0 = sm[i];
        float4 n1 = sm[i + 1];
        #pragma unroll
        for (int j = 0; j < P; ++j) {
            float s0 = fmaf(qx[j], c0.x, fmaf(qy[j], c0.y, fmaf(qz[j], c0.z, c0.w)));
            float s1 = fmaf(qx[j], c1.x, fmaf(qy[j], c1.y, fmaf(qz[j], c1.z, c1.w)));
            mn[j] = fminf(fminf(mn[j], s0), s1);   // -> v_min3_f32
        }
        c0 = n0; c1 = n1;
    }
    #pragma unroll
    for (int j = 0; j < P; ++j) {
        float s0 = fmaf(qx[j], c0.x, fmaf(qy[j], c0.y, fmaf(qz[j], c0.z, c0.w)));
        float s1 = fmaf(qx[j], c1.x, fmaf(qy[j], c1.y, fmaf(qz[j], c1.z, c1.w)));
        mn[j] = fminf(fminf(mn[j], s0), s1);
    }

    #pragma unroll
    for (int j = 0; j < P; ++j)
        partial[(size_t)cb * NROWS + row0 + threadIdx.x + j * 256] = mn[j];
}

template<int NCH>
__global__ __launch_bounds__(256) void reduce_kernel(
    const float4* __restrict__ packed, const float* __restrict__ partial,
    float* __restrict__ blockSums)
{
    int r = blockIdx.x * 256 + threadIdx.x;
    float m = 3.4e38f;
    #pragma unroll 8
    for (int c = 0; c < NCH; ++c)
        m = fminf(m, partial[(size_t)c * NROWS + r]);
    float val = m + packed[r].w;              // + ||p||^2

    __shared__ float red[256];
    red[threadIdx.x] = val;
    __syncthreads();
    for (int s = 128; s > 0; s >>= 1) {
        if (threadIdx.x < s) red[threadIdx.x] += red[threadIdx.x + s];
        __syncthreads();
    }
    if (threadIdx.x == 0) blockSums[blockIdx.x] = red[0];
}

__global__ __launch_bounds__(256) void final_kernel(
    const float* __restrict__ blockSums, float* __restrict__ out)
{
    __shared__ float red[256];
    red[threadIdx.x] = blockSums[threadIdx.x];
    __syncthreads();
    for (int s = 128; s > 0; s >>= 1) {
        if (threadIdx.x < s) red[threadIdx.x] += red[threadIdx.x + s];
        __syncthreads();
    }
    if (threadIdx.x == 0) out[0] = red[0] * (1.0f / (float)HALF);
}

template<int NCH>
static void run_pipeline(const float4* packed, char* ws, float* out, hipStream_t stream)
{
    float* partial   = (float*)(ws + (size_t)NROWS * sizeof(float4));
    float* blockSums = (float*)(ws + (size_t)NROWS * sizeof(float4)
                                   + (size_t)NROWS * NCH * sizeof(float));
    minpart_kernel<NCH><<<NRB * NCH, 256, 0, stream>>>(packed, partial);
    reduce_kernel<NCH><<<NROWS / 256, 256, 0, stream>>>(packed, partial, blockSums);
    final_kernel<<<1, 256, 0, stream>>>(blockSums, out);
}

extern "C" void kernel_launch(void* const* d_in, const int* in_sizes, int n_in,
                              void* d_out, int out_size, void* d_ws, size_t ws_size,
                              hipStream_t stream)
{
    const float* predict = (const float*)d_in[0];
    const float* target  = (const float*)d_in[1];
    float* out = (float*)d_out;

    char* ws = (char*)d_ws;
    float4* packed = (float4*)ws;                                  // 1 MB

    pack_kernel<<<NROWS / 256, 256, 0, stream>>>(predict, target, packed);

    const size_t base = (size_t)NROWS * sizeof(float4) + 4096;
    if (ws_size >= base + (size_t)NROWS * 64 * sizeof(float)) {
        run_pipeline<64>(packed, ws, out, stream);     // 1024 blocks, CW=128
    } else if (ws_size >= base + (size_t)NROWS * 32 * sizeof(float)) {
        run_pipeline<32>(packed, ws, out, stream);
    } else {
        run_pipeline<16>(packed, ws, out, stream);
    }
}

// Round 4
// 53.485 us; speedup vs baseline: 1.3162x; 1.3162x over previous
//
#include <hip/hip_runtime.h>

// Chamfer distance, fp32 brute force, VALU-bound.
// rows 0..32767    : predict points (b = r>>13), cols = target[b]
// rows 32768..65535: target points,              cols = predict[b]
// Per row: min over 8192 cols of (||t||^2 - 2 p.t), then + ||p||^2.
// out = (sum over all 65536 rows) / 32768.
//
// minpart: q=-2p per row; s = fma(qx,tx,fma(qy,ty,fma(qz,tz,tw))) = 3 fma;
// forced v_min3_f32 folds 2 cols -> 3.5 VALU/pair, ~24 us floor.
// Cross-chunk combine via deterministic atomicMin on monotone uint keys
// (min is order-independent -> bit-exact every replay), 256 KB not 16 MB.

#define NPTS   8192
#define HALF   32768            // 4 * NPTS
#define NROWS  65536
#define P      8                // rows per thread (32 VGPR row state)
#define RPB    2048             // rows per block = 256 * P
#define NRB    32               // NROWS / RPB
#define NCH    64               // col chunks -> 2048 blocks = 8/CU
#define CW     (NPTS / NCH)     // 128 cols per chunk

__device__ __forceinline__ float min3f(float a, float b, float c) {
    float d;
    asm("v_min3_f32 %0, %1, %2, %3" : "=v"(d) : "v"(a), "v"(b), "v"(c));
    return d;
}

// float -> order-preserving uint (for atomicMin)
__device__ __forceinline__ unsigned int fkey(float f) {
    unsigned int b = __float_as_uint(f);
    return (b & 0x80000000u) ? ~b : (b | 0x80000000u);
}
__device__ __forceinline__ float funkey(unsigned int k) {
    unsigned int b = (k & 0x80000000u) ? (k ^ 0x80000000u) : ~k;
    return __uint_as_float(b);
}

__global__ __launch_bounds__(256) void pack_kernel(
    const float* __restrict__ predict, const float* __restrict__ target,
    float4* __restrict__ packed, unsigned int* __restrict__ rowmin)
{
    int r = blockIdx.x * 256 + threadIdx.x;
    const float* src = (r < HALF) ? (predict + (size_t)r * 3)
                                  : (target + (size_t)(r - HALF) * 3);
    float x = src[0], y = src[1], z = src[2];
    float nrm = fmaf(x, x, fmaf(y, y, z * z));
    packed[r] = make_float4(x, y, z, nrm);
    rowmin[r] = 0xFFFFFFFFu;                  // +inf key
}

__global__ __launch_bounds__(256) void minpart_kernel(
    const float4* __restrict__ packed, unsigned int* __restrict__ rowmin)
{
    __shared__ float4 sm[CW];                 // 2 KB
    const int rb   = blockIdx.x / NCH;
    const int cb   = blockIdx.x % NCH;
    const int row0 = rb * RPB;
    const bool sideA = (row0 < HALF);
    const int local = sideA ? row0 : row0 - HALF;
    const int b = local >> 13;                // / NPTS
    const int colBase = (sideA ? HALF : 0) + (b << 13) + cb * CW;

    if (threadIdx.x < CW)
        sm[threadIdx.x] = packed[colBase + threadIdx.x];
    __syncthreads();

    float qx[P], qy[P], qz[P], mn[P];
    #pragma unroll
    for (int j = 0; j < P; ++j) {
        float4 p = packed[row0 + threadIdx.x + j * 256];
        qx[j] = -2.0f * p.x; qy[j] = -2.0f * p.y; qz[j] = -2.0f * p.z;
        mn[j] = 3.4e38f;
    }

    #pragma unroll 1
    for (int i = 0; i < CW; i += 4) {
        float4 t0 = sm[i + 0];                // uniform addr -> LDS broadcast
        float4 t1 = sm[i + 1];
        float4 t2 = sm[i + 2];
        float4 t3 = sm[i + 3];
        #pragma unroll
        for (int j = 0; j < P; ++j) {
            float s0 = fmaf(qx[j], t0.x, fmaf(qy[j], t0.y, fmaf(qz[j], t0.z, t0.w)));
            float s1 = fmaf(qx[j], t1.x, fmaf(qy[j], t1.y, fmaf(qz[j], t1.z, t1.w)));
            float s2 = fmaf(qx[j], t2.x, fmaf(qy[j], t2.y, fmaf(qz[j], t2.z, t2.w)));
            float s3 = fmaf(qx[j], t3.x, fmaf(qy[j], t3.y, fmaf(qz[j], t3.z, t3.w)));
            mn[j] = min3f(mn[j], s0, s1);
            mn[j] = min3f(mn[j], s2, s3);
        }
    }

    #pragma unroll
    for (int j = 0; j < P; ++j)
        atomicMin(&rowmin[row0 + threadIdx.x + j * 256], fkey(mn[j]));
}

__global__ __launch_bounds__(256) void reduce_kernel(
    const float4* __restrict__ packed, const unsigned int* __restrict__ rowmin,
    float* __restrict__ blockSums)
{
    int r = blockIdx.x * 256 + threadIdx.x;
    float val = funkey(rowmin[r]) + packed[r].w;   // + ||p||^2

    __shared__ float red[256];
    red[threadIdx.x] = val;
    __syncthreads();
    for (int s = 128; s > 0; s >>= 1) {
        if (threadIdx.x < s) red[threadIdx.x] += red[threadIdx.x + s];
        __syncthreads();
    }
    if (threadIdx.x == 0) blockSums[blockIdx.x] = red[0];
}

__global__ __launch_bounds__(256) void final_kernel(
    const float* __restrict__ blockSums, float* __restrict__ out)
{
    __shared__ float red[256];
    red[threadIdx.x] = blockSums[threadIdx.x];
    __syncthreads();
    for (int s = 128; s > 0; s >>= 1) {
        if (threadIdx.x < s) red[threadIdx.x] += red[threadIdx.x + s];
        __syncthreads();
    }
    if (threadIdx.x == 0) out[0] = red[0] * (1.0f / (float)HALF);
}

extern "C" void kernel_launch(void* const* d_in, const int* in_sizes, int n_in,
                              void* d_out, int out_size, void* d_ws, size_t ws_size,
                              hipStream_t stream)
{
    const float* predict = (const float*)d_in[0];
    const float* target  = (const float*)d_in[1];
    float* out = (float*)d_out;

    char* ws = (char*)d_ws;
    float4*       packed    = (float4*)ws;                              // 1 MB
    unsigned int* rowmin    = (unsigned int*)(ws + (size_t)NROWS * 16); // 256 KB
    float*        blockSums = (float*)(ws + (size_t)NROWS * 16
                                          + (size_t)NROWS * 4);         // 1 KB

    pack_kernel   <<<NROWS / 256, 256, 0, stream>>>(predict, target, packed, rowmin);
    minpart_kernel<<<NRB * NCH,   256, 0, stream>>>(packed, rowmin);
    reduce_kernel <<<NROWS / 256, 256, 0, stream>>>(packed, rowmin, blockSums);
    final_kernel  <<<1,           256, 0, stream>>>(blockSums, out);
}